// Round 2
// baseline (18489.360 us; speedup 1.0000x reference)
//
#include <hip/hip_runtime.h>
#include <hip/hip_bf16.h>

// B=16, T=1024, DA=1024, DV=512, DF=1536. Runtime dtype detection (f32 vs bf16).
// Structure: pdf weights are constant 1e-10 -> softmax exactly uniform in f32 ->
// res_av/res_va = per-batch mean projections; final L = blockdiag(chol(Sa+2e-6I),
// chol(Sv+2e-6I)); eps = jax.random.normal(key(42)) via threefry2x32 partitionable
// (bits = o0^o1 of threefry((0,42),(0,i))) + Giles erfinv, fused into out_kernel.

typedef unsigned short u16;
typedef unsigned int u32;

#define B_ 16
#define T_ 1024
#define DA_ 1024
#define DV_ 512
#define DF_ 1536

__device__ __forceinline__ float b2f(u16 x) {
    return __uint_as_float(((u32)x) << 16);
}
__device__ __forceinline__ u16 f2b(float x) {  // round-to-nearest-even
    u32 u = __float_as_uint(x);
    u32 r = (u + 0x7FFFu + ((u >> 16) & 1u)) >> 16;
    return (u16)r;
}
// dual-mode load: bf=1 -> bf16 element, bf=0 -> f32 element
__device__ __forceinline__ float ldx(const void* p, size_t i, int bf) {
    return bf ? b2f(((const u16*)p)[i]) : ((const float*)p)[i];
}

// ---------------- threefry2x32 (JAX key (0,42)), 20 rounds ----------------
__device__ __forceinline__ u32 rotl32(u32 x, int r) { return (x << r) | (x >> (32 - r)); }

__device__ __forceinline__ void threefry2x32(u32 k0, u32 k1, u32 x0, u32 x1,
                                             u32* o0, u32* o1) {
    u32 ks0 = k0, ks1 = k1, ks2 = k0 ^ k1 ^ 0x1BD11BDAu;
    x0 += ks0; x1 += ks1;
#define TF_R4(a,b,c,d)                                     \
    x0 += x1; x1 = rotl32(x1,a); x1 ^= x0;                 \
    x0 += x1; x1 = rotl32(x1,b); x1 ^= x0;                 \
    x0 += x1; x1 = rotl32(x1,c); x1 ^= x0;                 \
    x0 += x1; x1 = rotl32(x1,d); x1 ^= x0;
    TF_R4(13,15,26,6)  x0 += ks1; x1 += ks2 + 1u;
    TF_R4(17,29,16,24) x0 += ks2; x1 += ks0 + 2u;
    TF_R4(13,15,26,6)  x0 += ks0; x1 += ks1 + 3u;
    TF_R4(17,29,16,24) x0 += ks1; x1 += ks2 + 4u;
    TF_R4(13,15,26,6)  x0 += ks2; x1 += ks0 + 5u;
#undef TF_R4
    *o0 = x0; *o1 = x1;
}

// Giles erfinv polynomial (matches XLA ErfInv32)
__device__ __forceinline__ float erfinv_f(float u) {
    float w = -log1pf(-u * u);
    float p;
    if (w < 5.0f) {
        w -= 2.5f;
        p = 2.81022636e-08f;
        p = fmaf(p, w, 3.43273939e-07f);
        p = fmaf(p, w, -3.5233877e-06f);
        p = fmaf(p, w, -4.39150654e-06f);
        p = fmaf(p, w, 0.00021858087f);
        p = fmaf(p, w, -0.00125372503f);
        p = fmaf(p, w, -0.00417768164f);
        p = fmaf(p, w, 0.246640727f);
        p = fmaf(p, w, 1.50140941f);
    } else {
        w = sqrtf(w) - 3.0f;
        p = -0.000200214257f;
        p = fmaf(p, w, 0.000100950558f);
        p = fmaf(p, w, 0.00134934322f);
        p = fmaf(p, w, -0.00367342844f);
        p = fmaf(p, w, 0.00573950773f);
        p = fmaf(p, w, -0.0076224613f);
        p = fmaf(p, w, 0.00943887047f);
        p = fmaf(p, w, 1.00167406f);
        p = fmaf(p, w, 2.83297682f);
    }
    return p * u;
}

__device__ __forceinline__ float gen_eps(u32 i) {
    u32 o0, o1;
    threefry2x32(0u, 42u, 0u, i, &o0, &o1);
    u32 bits = o0 ^ o1;  // jax partitionable path, bit_width=32, hi32(count)=0
    float f = __uint_as_float((bits >> 9) | 0x3F800000u) - 1.0f;
    float lo = __uint_as_float(0xBF7FFFFFu);  // nextafter(-1,0)
    float u = fmaxf(lo, f * 2.0f + lo);       // (hi-lo) rounds to exactly 2.0f
    return __uint_as_float(0x3FB504F3u) * erfinv_f(u);  // sqrt(2)_f32 * erfinv
}

// ---------------- dtype detection ----------------
__global__ void detect_kernel(const void* __restrict__ A, int* __restrict__ flag) {
    if (threadIdx.x == 0 && blockIdx.x == 0) {
        int bf = 1;
        for (int i = 0; i < 128; ++i) {
            float v = b2f(((const u16*)A)[i]);
            if (!(fabsf(v) < 1e4f)) bf = 0;  // f32 mantissa words decode huge/NaN
        }
        *flag = bf;
    }
}

// ---------------- means over T ----------------
__global__ __launch_bounds__(256) void means_kernel(const void* __restrict__ A,
                                                    const void* __restrict__ V,
                                                    float* __restrict__ mu_a,
                                                    float* __restrict__ mu_v,
                                                    const int* __restrict__ flag) {
    int bf = *flag;
    int gid = blockIdx.x * 256 + threadIdx.x;  // 16*1536 threads
    int b = gid / DF_, r = gid % DF_;
    if (r < DA_) {
        size_t base = ((size_t)b << 20) + r;
        float s = 0.f;
        for (int t = 0; t < T_; ++t) s += ldx(A, base + ((size_t)t << 10), bf);
        mu_a[b * DA_ + r] = s / 1024.0f;
    } else {
        int rr = r - DA_;
        size_t base = (size_t)b * (T_ * DV_) + rr;
        float s = 0.f;
        for (int t = 0; t < T_; ++t) s += ldx(V, base + t * DV_, bf);
        mu_v[b * DV_ + rr] = s / 1024.0f;
    }
}

// ---------------- centered Gram: S = Xc^T Xc / 1023 + 2e-6 I (lower tiles) ------
__global__ __launch_bounds__(256) void gram_kernel(const void* __restrict__ X,
                                                   const float* __restrict__ mu,
                                                   float* __restrict__ Sout, int D,
                                                   const int* __restrict__ flag) {
    int bj = blockIdx.x, bi = blockIdx.y, b = blockIdx.z;
    if (bj > bi) return;  // lower-triangular block grid
    int bf = *flag;
    int i0 = bi * 64, j0 = bj * 64;
    size_t Xb = (size_t)b * T_ * D;
    const float* mub = mu + b * D;
    __shared__ float Xi[16][65], Xj[16][65];
    __shared__ float mi[64], mj[64];
    int tid = threadIdx.x;
    if (tid < 64) mi[tid] = mub[i0 + tid];
    else if (tid < 128) mj[tid - 64] = mub[j0 + tid - 64];
    __syncthreads();
    float acc[4][4] = {};
    int tx = tid & 15, ty = tid >> 4;
    for (int t0 = 0; t0 < T_; t0 += 16) {
        for (int r = 0; r < 4; ++r) {
            int lin = tid + r * 256, kk = lin >> 6, ii = lin & 63;
            Xi[kk][ii] = ldx(X, Xb + (size_t)(t0 + kk) * D + i0 + ii, bf) - mi[ii];
            Xj[kk][ii] = ldx(X, Xb + (size_t)(t0 + kk) * D + j0 + ii, bf) - mj[ii];
        }
        __syncthreads();
#pragma unroll
        for (int kk = 0; kk < 16; ++kk) {
            float xi[4], xj[4];
#pragma unroll
            for (int u = 0; u < 4; ++u) { xi[u] = Xi[kk][ty * 4 + u]; xj[u] = Xj[kk][tx * 4 + u]; }
#pragma unroll
            for (int u = 0; u < 4; ++u)
#pragma unroll
                for (int v = 0; v < 4; ++v) acc[u][v] += xi[u] * xj[v];
        }
        __syncthreads();
    }
    float* Sb = Sout + (size_t)b * D * D;
#pragma unroll
    for (int u = 0; u < 4; ++u)
#pragma unroll
        for (int v = 0; v < 4; ++v) {
            int i = i0 + ty * 4 + u, j = j0 + tx * 4 + v;
            float val = acc[u][v] / 1023.0f;
            if (i == j) val += 2e-6f;  // batch_cov eps + final chol eps
            Sb[(size_t)i * D + j] = val;
        }
}

// ---------------- batched in-place blocked Cholesky (one workgroup/matrix) ------
__global__ __launch_bounds__(1024) void chol_kernel(float* __restrict__ SA,
                                                    float* __restrict__ SV) {
    int mb = blockIdx.x;
    float* S;
    int d;
    if (mb < 16) { S = SA + ((size_t)mb << 20); d = 1024; }
    else         { S = SV + (size_t)(mb - 16) * (512 * 512); d = 512; }
    int tid = threadIdx.x;
    int lane = tid & 63, wv = tid >> 6;  // 16 waves
    __shared__ float Lk[64][65];
    __shared__ float Dblk[64][65];

    for (int k0 = 0; k0 < d; k0 += 64) {
        // Phase A: left-looking panel update, cols [k0,k0+64), rows [k0,d)
        int nIg = (d - k0) >> 6;
        for (int ig = 0; ig < nIg; ++ig) {
            int ibase = k0 + ig * 64 + wv * 4;
            float acc[4];
#pragma unroll
            for (int r = 0; r < 4; ++r) acc[r] = S[(size_t)(ibase + r) * d + k0 + lane];
            for (int j0 = 0; j0 < k0; j0 += 64) {
                __syncthreads();
                for (int l = tid; l < 4096; l += 1024) {
                    int cc = l >> 6, jj = l & 63;
                    Lk[cc][jj] = S[(size_t)(k0 + cc) * d + j0 + jj];
                }
                __syncthreads();
#pragma unroll 4
                for (int jj = 0; jj < 64; ++jj) {
                    float lkv = Lk[lane][jj];
#pragma unroll
                    for (int r = 0; r < 4; ++r)
                        acc[r] -= S[(size_t)(ibase + r) * d + j0 + jj] * lkv;
                }
            }
#pragma unroll
            for (int r = 0; r < 4; ++r) S[(size_t)(ibase + r) * d + k0 + lane] = acc[r];
        }
        __syncthreads();
        // Phase B: factor 64x64 diagonal block in LDS
        for (int l = tid; l < 4096; l += 1024) {
            int rr = l >> 6, cc = l & 63;
            Dblk[rr][cc] = S[(size_t)(k0 + rr) * d + k0 + cc];
        }
        __syncthreads();
        for (int cc = 0; cc < 64; ++cc) {
            float x = Dblk[cc][cc];
            float piv = sqrtf(fmaxf(x, 1e-8f));  // floor vs f32 noise on near-singular Sa
            __syncthreads();
            if (tid == 0) Dblk[cc][cc] = piv;
            if (tid > cc && tid < 64) Dblk[tid][cc] = Dblk[tid][cc] / piv;
            __syncthreads();
            for (int l = tid; l < 4096; l += 1024) {
                int rr = l >> 6, c2 = l & 63;
                if (rr > cc && c2 > cc && c2 <= rr)
                    Dblk[rr][c2] -= Dblk[rr][cc] * Dblk[c2][cc];
            }
            __syncthreads();
        }
        for (int l = tid; l < 4096; l += 1024) {  // write back lower+diag
            int rr = l >> 6, cc = l & 63;
            if (cc <= rr) S[(size_t)(k0 + rr) * d + k0 + cc] = Dblk[rr][cc];
        }
        // Phase C: triangular solve for rows below the diagonal block
        int rows = d - k0 - 64;
        if (tid < rows) {
            size_t base = (size_t)(k0 + 64 + tid) * d + k0;
            for (int c = 0; c < 64; ++c) {
                float v = S[base + c];
                for (int j = 0; j < c; ++j) v -= S[base + j] * Dblk[c][j];
                S[base + c] = v / Dblk[c][c];
            }
        }
        __syncthreads();
    }
    // zero strict upper triangle so the output GEMM can run dense tiles
    for (int r = 0; r < d; ++r)
        for (int cc = r + 1 + tid; cc < d; cc += 1024) S[(size_t)r * d + cc] = 0.f;
}

// ---------------- res_av / res_va from means (attention collapsed) --------------
__global__ __launch_bounds__(256) void proj_mu_kernel(
    const float* __restrict__ mu_a, const float* __restrict__ mu_v,
    const void* __restrict__ Vvw, const void* __restrict__ Vvb,
    const void* __restrict__ Vaw, const void* __restrict__ Vab,
    float* __restrict__ res_av, float* __restrict__ res_va,
    const int* __restrict__ flag) {
    int bf = *flag;
    int b = blockIdx.x, tid = threadIdx.x;
    __shared__ float mv[DV_], ma[DA_];
    for (int i = tid; i < DV_; i += 256) mv[i] = mu_v[b * DV_ + i];
    for (int i = tid; i < DA_; i += 256) ma[i] = mu_a[b * DA_ + i];
    __syncthreads();
    for (int j = tid; j < DV_; j += 256) {
        size_t w = (size_t)j * DV_;
        float s = 0.f;
#pragma unroll 8
        for (int k = 0; k < DV_; ++k) s += mv[k] * ldx(Vvw, w + k, bf);
        res_av[b * DV_ + j] = s + ldx(Vvb, j, bf);
    }
    for (int j = tid; j < DA_; j += 256) {
        size_t w = (size_t)j * DA_;
        float s = 0.f;
#pragma unroll 8
        for (int k = 0; k < DA_; ++k) s += ma[k] * ldx(Vaw, w + k, bf);
        res_va[b * DA_ + j] = s + ldx(Vab, j, bf);
    }
}

// ---------------- lin_av / lin_va and gate constants ----------------------------
__global__ __launch_bounds__(256) void proj_res_kernel(
    const float* __restrict__ res_av, const float* __restrict__ res_va,
    const void* __restrict__ v2aw, const void* __restrict__ v2ab,
    const void* __restrict__ a2vw, const void* __restrict__ a2vb,
    const void* __restrict__ WAg, const void* __restrict__ bAg,
    const void* __restrict__ WVg, const void* __restrict__ bVg,
    float* __restrict__ lin_av, float* __restrict__ lin_va,
    float* __restrict__ gca, float* __restrict__ gcv,
    const int* __restrict__ flag) {
    int bf = *flag;
    int b = blockIdx.x, tid = threadIdx.x;
    __shared__ float rav[DV_], rva[DA_];
    __shared__ float red[256];
    for (int i = tid; i < DV_; i += 256) rav[i] = res_av[b * DV_ + i];
    for (int i = tid; i < DA_; i += 256) rva[i] = res_va[b * DA_ + i];
    __syncthreads();
    for (int dd = tid; dd < DA_; dd += 256) {
        size_t w = (size_t)dd * DV_;
        float s = 0.f;
#pragma unroll 8
        for (int k = 0; k < DV_; ++k) s += rav[k] * ldx(v2aw, w + k, bf);
        lin_av[b * DA_ + dd] = s + ldx(v2ab, dd, bf);
    }
    for (int dd = tid; dd < DV_; dd += 256) {
        size_t w = (size_t)dd * DA_;
        float s = 0.f;
#pragma unroll 8
        for (int k = 0; k < DA_; ++k) s += rva[k] * ldx(a2vw, w + k, bf);
        lin_va[b * DV_ + dd] = s + ldx(a2vb, dd, bf);
    }
    float pa = 0.f, pv = 0.f;
    for (int k = tid; k < DV_; k += 256) pa += rav[k] * ldx(WAg, DA_ + k, bf);
    for (int k = tid; k < DA_; k += 256) pv += rva[k] * ldx(WVg, DV_ + k, bf);
    red[tid] = pa; __syncthreads();
    for (int s = 128; s > 0; s >>= 1) { if (tid < s) red[tid] += red[tid + s]; __syncthreads(); }
    if (tid == 0) gca[b] = red[0] + ldx(bAg, 0, bf);
    __syncthreads();
    red[tid] = pv; __syncthreads();
    for (int s = 128; s > 0; s >>= 1) { if (tid < s) red[tid] += red[tid + s]; __syncthreads(); }
    if (tid == 0) gcv[b] = red[0] + ldx(bVg, 0, bf);
}

// ---------------- per-token gates -----------------------------------------------
__global__ __launch_bounds__(256) void gates_kernel(
    const void* __restrict__ A, const void* __restrict__ V,
    const void* __restrict__ WAg, const void* __restrict__ WVg,
    const float* __restrict__ gca, const float* __restrict__ gcv,
    float* __restrict__ g_a, float* __restrict__ g_v,
    const int* __restrict__ flag) {
    int bf = *flag;
    int bt = blockIdx.x;  // b*1024+t
    int b = bt >> 10;
    int tid = threadIdx.x;
    size_t Ar = (size_t)bt * DA_;
    size_t Vr = (size_t)bt * DV_;
    float sa = 0.f, sv = 0.f;
    for (int dd = tid; dd < DA_; dd += 256) sa += ldx(A, Ar + dd, bf) * ldx(WAg, dd, bf);
    for (int dd = tid; dd < DV_; dd += 256) sv += ldx(V, Vr + dd, bf) * ldx(WVg, dd, bf);
    __shared__ float ra[256], rv[256];
    ra[tid] = sa; rv[tid] = sv; __syncthreads();
    for (int s = 128; s > 0; s >>= 1) {
        if (tid < s) { ra[tid] += ra[tid + s]; rv[tid] += rv[tid + s]; }
        __syncthreads();
    }
    if (tid == 0) {
        g_a[bt] = 1.f / (1.f + expf(-(ra[0] + gca[b])));
        g_v[bt] = 1.f / (1.f + expf(-(rv[0] + gcv[b])));
    }
}

// ---- output: out = g*X + (1-g)*lin + eps @ L^T, eps generated inline -----------
__global__ __launch_bounds__(256) void out_kernel(
    const float* __restrict__ L, int D,
    const void* __restrict__ X, const float* __restrict__ g,
    const float* __restrict__ lin, void* __restrict__ out, int ocol0, int eoff,
    const int* __restrict__ flag) {
    int bf = *flag;
    int b = blockIdx.z;
    int t0 = blockIdx.x * 64, d0 = blockIdx.y * 64;
    int tid = threadIdx.x, tx = tid & 15, ty = tid >> 4;
    __shared__ float Et[16][65], Lt[16][65];
    const float* Lb = L + (size_t)b * D * D;
    float acc[4][4] = {};
    int emax = d0 + 64;  // L lower-triangular (upper zeroed) -> skip tiles above diag
    if (emax > D) emax = D;
    int row = tid >> 2, quad = tid & 3;
    for (int e0 = 0; e0 < emax; e0 += 16) {
        u32 ebase = ((u32)b * T_ + (u32)(t0 + row)) * (u32)DF_ + (u32)(eoff + e0 + quad * 4);
        const float* lp = Lb + (size_t)(d0 + row) * D + e0 + quad * 4;
#pragma unroll
        for (int u = 0; u < 4; ++u) {
            Et[quad * 4 + u][row] = gen_eps(ebase + u);
            Lt[quad * 4 + u][row] = lp[u];
        }
        __syncthreads();
#pragma unroll
        for (int kk = 0; kk < 16; ++kk) {
            float ev[4], lv[4];
#pragma unroll
            for (int u = 0; u < 4; ++u) { ev[u] = Et[kk][ty * 4 + u]; lv[u] = Lt[kk][tx * 4 + u]; }
#pragma unroll
            for (int u = 0; u < 4; ++u)
#pragma unroll
                for (int v = 0; v < 4; ++v) acc[u][v] += ev[u] * lv[v];
        }
        __syncthreads();
    }
#pragma unroll
    for (int u = 0; u < 4; ++u) {
        int t = t0 + ty * 4 + u;
        float gv = g[b * T_ + t];
        size_t Xrow = ((size_t)b * T_ + t) * D;
        size_t orow = ((size_t)b * T_ + t) * DF_ + ocol0;
#pragma unroll
        for (int v = 0; v < 4; ++v) {
            int dd = d0 + tx * 4 + v;
            float val = gv * ldx(X, Xrow + dd, bf) + (1.f - gv) * lin[b * D + dd] + acc[u][v];
            if (bf) ((u16*)out)[orow + dd] = f2b(val);
            else    ((float*)out)[orow + dd] = val;
        }
    }
}

extern "C" void kernel_launch(void* const* d_in, const int* in_sizes, int n_in,
                              void* d_out, int out_size, void* d_ws, size_t ws_size,
                              hipStream_t stream) {
    (void)in_sizes; (void)n_in; (void)out_size; (void)ws_size;
    const void* A    = d_in[0];
    const void* V    = d_in[1];
    const void* Vvw  = d_in[6];   // V_v_w
    const void* Vvb  = d_in[7];
    const void* Vaw  = d_in[12];  // V_a_w
    const void* Vab  = d_in[13];
    const void* WAg  = d_in[14];
    const void* bAg  = d_in[15];
    const void* WVg  = d_in[16];
    const void* bVg  = d_in[17];
    const void* v2aw = d_in[18];
    const void* v2ab = d_in[19];
    const void* a2vw = d_in[20];
    const void* a2vb = d_in[21];

    float* ws     = (float*)d_ws;
    float* LA     = ws;                    // 16*1024*1024
    float* LV     = LA + 16777216;         // 16*512*512
    float* mu_a   = LV + 4194304;          // 16*1024
    float* mu_v   = mu_a + 16384;          // 16*512
    float* res_av = mu_v + 8192;           // 16*512
    float* res_va = res_av + 8192;         // 16*1024
    float* lin_av = res_va + 16384;        // 16*1024
    float* lin_va = lin_av + 16384;        // 16*512
    float* gca    = lin_va + 8192;         // 16
    float* gcv    = gca + 16;              // 16
    float* g_a    = gcv + 16;              // 16*1024
    float* g_v    = g_a + 16384;           // 16*1024
    int*   dtf    = (int*)(g_v + 16384);
    // total ~84.3 MB of workspace

    detect_kernel<<<dim3(1), dim3(64), 0, stream>>>(A, dtf);
    means_kernel<<<dim3(96), dim3(256), 0, stream>>>(A, V, mu_a, mu_v, dtf);
    gram_kernel<<<dim3(16, 16, 16), dim3(256), 0, stream>>>(A, mu_a, LA, 1024, dtf);
    gram_kernel<<<dim3(8, 8, 16), dim3(256), 0, stream>>>(V, mu_v, LV, 512, dtf);
    chol_kernel<<<dim3(32), dim3(1024), 0, stream>>>(LA, LV);
    proj_mu_kernel<<<dim3(16), dim3(256), 0, stream>>>(mu_a, mu_v, Vvw, Vvb, Vaw, Vab,
                                                       res_av, res_va, dtf);
    proj_res_kernel<<<dim3(16), dim3(256), 0, stream>>>(res_av, res_va, v2aw, v2ab,
                                                        a2vw, a2vb, WAg, bAg, WVg, bVg,
                                                        lin_av, lin_va, gca, gcv, dtf);
    gates_kernel<<<dim3(16384), dim3(256), 0, stream>>>(A, V, WAg, WVg, gca, gcv,
                                                        g_a, g_v, dtf);
    out_kernel<<<dim3(16, 16, 16), dim3(256), 0, stream>>>(LA, 1024, A, g_a,
                                                           lin_av, d_out, 0, 0, dtf);
    out_kernel<<<dim3(16, 8, 16), dim3(256), 0, stream>>>(LV, 512, V, g_v,
                                                          lin_va, d_out, 1024, 1024, dtf);
}

// Round 3
// 7998.602 us; speedup vs baseline: 2.3116x; 2.3116x over previous
//
#include <hip/hip_runtime.h>
#include <hip/hip_bf16.h>

// B=16, T=1024, DA=1024, DV=512, DF=1536. Runtime dtype detection (f32 vs bf16).
// Structure: pdf weights are constant 1e-10 -> softmax exactly uniform in f32 ->
// res_av/res_va = per-batch mean projections; final L = blockdiag(chol(Sa+2e-6I),
// chol(Sv+2e-6I)); eps = jax.random.normal(key(42)) via threefry2x32 partitionable
// (bits = o0^o1 of threefry((0,42),(0,i))) + Giles erfinv, fused into out_kernel.
// R2: Cholesky restructured from 1-kernel left-looking (14.3ms, 3.7% occupancy) to
// multi-launch right-looking blocked (panel + trailing-update kernels).

typedef unsigned short u16;
typedef unsigned int u32;

#define B_ 16
#define T_ 1024
#define DA_ 1024
#define DV_ 512
#define DF_ 1536

__device__ __forceinline__ float b2f(u16 x) {
    return __uint_as_float(((u32)x) << 16);
}
__device__ __forceinline__ u16 f2b(float x) {  // round-to-nearest-even
    u32 u = __float_as_uint(x);
    u32 r = (u + 0x7FFFu + ((u >> 16) & 1u)) >> 16;
    return (u16)r;
}
// dual-mode load: bf=1 -> bf16 element, bf=0 -> f32 element
__device__ __forceinline__ float ldx(const void* p, size_t i, int bf) {
    return bf ? b2f(((const u16*)p)[i]) : ((const float*)p)[i];
}

// ---------------- threefry2x32 (JAX key (0,42)), 20 rounds ----------------
__device__ __forceinline__ u32 rotl32(u32 x, int r) { return (x << r) | (x >> (32 - r)); }

__device__ __forceinline__ void threefry2x32(u32 k0, u32 k1, u32 x0, u32 x1,
                                             u32* o0, u32* o1) {
    u32 ks0 = k0, ks1 = k1, ks2 = k0 ^ k1 ^ 0x1BD11BDAu;
    x0 += ks0; x1 += ks1;
#define TF_R4(a,b,c,d)                                     \
    x0 += x1; x1 = rotl32(x1,a); x1 ^= x0;                 \
    x0 += x1; x1 = rotl32(x1,b); x1 ^= x0;                 \
    x0 += x1; x1 = rotl32(x1,c); x1 ^= x0;                 \
    x0 += x1; x1 = rotl32(x1,d); x1 ^= x0;
    TF_R4(13,15,26,6)  x0 += ks1; x1 += ks2 + 1u;
    TF_R4(17,29,16,24) x0 += ks2; x1 += ks0 + 2u;
    TF_R4(13,15,26,6)  x0 += ks0; x1 += ks1 + 3u;
    TF_R4(17,29,16,24) x0 += ks1; x1 += ks2 + 4u;
    TF_R4(13,15,26,6)  x0 += ks2; x1 += ks0 + 5u;
#undef TF_R4
    *o0 = x0; *o1 = x1;
}

// Giles erfinv polynomial (matches XLA ErfInv32)
__device__ __forceinline__ float erfinv_f(float u) {
    float w = -log1pf(-u * u);
    float p;
    if (w < 5.0f) {
        w -= 2.5f;
        p = 2.81022636e-08f;
        p = fmaf(p, w, 3.43273939e-07f);
        p = fmaf(p, w, -3.5233877e-06f);
        p = fmaf(p, w, -4.39150654e-06f);
        p = fmaf(p, w, 0.00021858087f);
        p = fmaf(p, w, -0.00125372503f);
        p = fmaf(p, w, -0.00417768164f);
        p = fmaf(p, w, 0.246640727f);
        p = fmaf(p, w, 1.50140941f);
    } else {
        w = sqrtf(w) - 3.0f;
        p = -0.000200214257f;
        p = fmaf(p, w, 0.000100950558f);
        p = fmaf(p, w, 0.00134934322f);
        p = fmaf(p, w, -0.00367342844f);
        p = fmaf(p, w, 0.00573950773f);
        p = fmaf(p, w, -0.0076224613f);
        p = fmaf(p, w, 0.00943887047f);
        p = fmaf(p, w, 1.00167406f);
        p = fmaf(p, w, 2.83297682f);
    }
    return p * u;
}

__device__ __forceinline__ float gen_eps(u32 i) {
    u32 o0, o1;
    threefry2x32(0u, 42u, 0u, i, &o0, &o1);
    u32 bits = o0 ^ o1;  // jax partitionable path, bit_width=32, hi32(count)=0
    float f = __uint_as_float((bits >> 9) | 0x3F800000u) - 1.0f;
    float lo = __uint_as_float(0xBF7FFFFFu);  // nextafter(-1,0)
    float u = fmaxf(lo, f * 2.0f + lo);       // (hi-lo) rounds to exactly 2.0f
    return __uint_as_float(0x3FB504F3u) * erfinv_f(u);  // sqrt(2)_f32 * erfinv
}

// ---------------- dtype detection ----------------
__global__ void detect_kernel(const void* __restrict__ A, int* __restrict__ flag) {
    if (threadIdx.x == 0 && blockIdx.x == 0) {
        int bf = 1;
        for (int i = 0; i < 128; ++i) {
            float v = b2f(((const u16*)A)[i]);
            if (!(fabsf(v) < 1e4f)) bf = 0;  // f32 mantissa words decode huge/NaN
        }
        *flag = bf;
    }
}

// ---------------- means over T ----------------
__global__ __launch_bounds__(256) void means_kernel(const void* __restrict__ A,
                                                    const void* __restrict__ V,
                                                    float* __restrict__ mu_a,
                                                    float* __restrict__ mu_v,
                                                    const int* __restrict__ flag) {
    int bf = *flag;
    int gid = blockIdx.x * 256 + threadIdx.x;  // 16*1536 threads
    int b = gid / DF_, r = gid % DF_;
    if (r < DA_) {
        size_t base = ((size_t)b << 20) + r;
        float s = 0.f;
        for (int t = 0; t < T_; ++t) s += ldx(A, base + ((size_t)t << 10), bf);
        mu_a[b * DA_ + r] = s / 1024.0f;
    } else {
        int rr = r - DA_;
        size_t base = (size_t)b * (T_ * DV_) + rr;
        float s = 0.f;
        for (int t = 0; t < T_; ++t) s += ldx(V, base + t * DV_, bf);
        mu_v[b * DV_ + rr] = s / 1024.0f;
    }
}

// ---------------- centered Gram: S = Xc^T Xc / 1023 + 2e-6 I (lower tiles) ------
__global__ __launch_bounds__(256) void gram_kernel(const void* __restrict__ X,
                                                   const float* __restrict__ mu,
                                                   float* __restrict__ Sout, int D,
                                                   const int* __restrict__ flag) {
    int bj = blockIdx.x, bi = blockIdx.y, b = blockIdx.z;
    if (bj > bi) return;  // lower-triangular block grid
    int bf = *flag;
    int i0 = bi * 64, j0 = bj * 64;
    size_t Xb = (size_t)b * T_ * D;
    const float* mub = mu + b * D;
    __shared__ float Xi[16][65], Xj[16][65];
    __shared__ float mi[64], mj[64];
    int tid = threadIdx.x;
    if (tid < 64) mi[tid] = mub[i0 + tid];
    else if (tid < 128) mj[tid - 64] = mub[j0 + tid - 64];
    __syncthreads();
    float acc[4][4] = {};
    int tx = tid & 15, ty = tid >> 4;
    for (int t0 = 0; t0 < T_; t0 += 16) {
        for (int r = 0; r < 4; ++r) {
            int lin = tid + r * 256, kk = lin >> 6, ii = lin & 63;
            Xi[kk][ii] = ldx(X, Xb + (size_t)(t0 + kk) * D + i0 + ii, bf) - mi[ii];
            Xj[kk][ii] = ldx(X, Xb + (size_t)(t0 + kk) * D + j0 + ii, bf) - mj[ii];
        }
        __syncthreads();
#pragma unroll
        for (int kk = 0; kk < 16; ++kk) {
            float xi[4], xj[4];
#pragma unroll
            for (int u = 0; u < 4; ++u) { xi[u] = Xi[kk][ty * 4 + u]; xj[u] = Xj[kk][tx * 4 + u]; }
#pragma unroll
            for (int u = 0; u < 4; ++u)
#pragma unroll
                for (int v = 0; v < 4; ++v) acc[u][v] += xi[u] * xj[v];
        }
        __syncthreads();
    }
    float* Sb = Sout + (size_t)b * D * D;
#pragma unroll
    for (int u = 0; u < 4; ++u)
#pragma unroll
        for (int v = 0; v < 4; ++v) {
            int i = i0 + ty * 4 + u, j = j0 + tx * 4 + v;
            float val = acc[u][v] / 1023.0f;
            if (i == j) val += 2e-6f;  // batch_cov eps + final chol eps
            Sb[(size_t)i * D + j] = val;
        }
}

// ---- Cholesky step 1: factor 64x64 diagonal block + TRSM of the panel below ----
// One block per matrix (32 blocks). Triangular elements of the diagonal block are
// held in registers; LDS Dblk is the publication buffer (2 barriers per column).
__global__ __launch_bounds__(256) void panel_kernel(float* __restrict__ SA,
                                                    float* __restrict__ SV, int step) {
    int mb = blockIdx.x;
    float* S; int d;
    if (mb < 16) { S = SA + ((size_t)mb << 20); d = 1024; }
    else         { S = SV + (size_t)(mb - 16) * (512 * 512); d = 512; }
    int k0 = step * 64;
    if (k0 >= d) return;
    int tid = threadIdx.x;
    __shared__ float Dblk[64][65];
    for (int l = tid; l < 4096; l += 256) {
        int r = l >> 6, c = l & 63;
        Dblk[r][c] = S[(size_t)(k0 + r) * d + k0 + c];
    }
    __syncthreads();
    // static ownership of the 2080 lower-triangular elements (9 slots/thread)
    float val[9]; int er[9], ej[9];
#pragma unroll
    for (int e = 0; e < 9; ++e) {
        int l = tid + e * 256;
        if (l < 2080) {
            int r = (int)((sqrtf(8.f * (float)l + 1.f) - 1.f) * 0.5f);
            while ((r + 1) * (r + 2) / 2 <= l) ++r;
            while (r * (r + 1) / 2 > l) --r;
            int j = l - r * (r + 1) / 2;
            er[e] = r; ej[e] = j; val[e] = Dblk[r][j];
        } else { er[e] = -1; ej[e] = -1; val[e] = 0.f; }
    }
    for (int c = 0; c < 64; ++c) {
        // publish raw diagonal (owner thread; value final after prior updates)
#pragma unroll
        for (int e = 0; e < 9; ++e)
            if (er[e] == c && ej[e] == c) Dblk[c][c] = val[e];
        __syncthreads();
        float piv = sqrtf(fmaxf(Dblk[c][c], 1e-8f));  // same floor as R1 (passed)
#pragma unroll
        for (int e = 0; e < 9; ++e) {
            if (ej[e] == c) {
                if (er[e] == c) val[e] = piv;
                else { val[e] /= piv; Dblk[er[e]][c] = val[e]; }
            }
        }
        __syncthreads();
#pragma unroll
        for (int e = 0; e < 9; ++e)
            if (ej[e] > c) val[e] -= Dblk[er[e]][c] * Dblk[ej[e]][c];
    }
    __syncthreads();
    // publish diagonal piv values (off-diag columns already published)
#pragma unroll
    for (int e = 0; e < 9; ++e)
        if (er[e] >= 0 && er[e] == ej[e]) Dblk[er[e]][er[e]] = val[e];
    __syncthreads();
    // write back D block: lower/diag = L, upper = 0 (so out_kernel's diag band is clean)
    for (int l = tid; l < 4096; l += 256) {
        int r = l >> 6, c = l & 63;
        S[(size_t)(k0 + r) * d + k0 + c] = (c <= r) ? Dblk[r][c] : 0.f;
    }
    // TRSM: rows below the block solve L_D * y^T = row^T, row cached in registers
    for (int row = k0 + 64 + tid; row < d; row += 256) {
        size_t base = (size_t)row * d + k0;
        float v[64];
#pragma unroll
        for (int c4 = 0; c4 < 64; c4 += 4) {
            float4 t = *(const float4*)&S[base + c4];
            v[c4] = t.x; v[c4 + 1] = t.y; v[c4 + 2] = t.z; v[c4 + 3] = t.w;
        }
#pragma unroll
        for (int c = 0; c < 64; ++c) {
            float s = v[c];
#pragma unroll
            for (int j = 0; j < c; ++j) s -= v[j] * Dblk[c][j];
            v[c] = s / Dblk[c][c];
        }
#pragma unroll
        for (int c4 = 0; c4 < 64; c4 += 4) {
            float4 t; t.x = v[c4]; t.y = v[c4 + 1]; t.z = v[c4 + 2]; t.w = v[c4 + 3];
            *(float4*)&S[base + c4] = t;
        }
    }
}

// ---- Cholesky step 2: trailing update S22 -= L21 * L21^T, 64x64 tiles ----------
__global__ __launch_bounds__(256) void trail_kernel(float* __restrict__ SA,
                                                    float* __restrict__ SV, int step) {
    int mb = blockIdx.z;
    float* S; int d;
    if (mb < 16) { S = SA + ((size_t)mb << 20); d = 1024; }
    else         { S = SV + (size_t)(mb - 16) * (512 * 512); d = 512; }
    int k0 = step * 64;
    int t0 = k0 + 64;
    int m = (d - t0) >> 6;
    if (m <= 0) return;
    int ntiles = m * (m + 1) / 2;
    int x = blockIdx.x;
    if (x >= ntiles) return;
    int bi = (int)((sqrtf(8.f * (float)x + 1.f) - 1.f) * 0.5f);
    while ((bi + 1) * (bi + 2) / 2 <= x) ++bi;
    while (bi * (bi + 1) / 2 > x) --bi;
    int bj = x - bi * (bi + 1) / 2;
    int i0 = t0 + bi * 64, j0 = t0 + bj * 64;
    __shared__ float Ai[64][65], Aj[64][65];
    int tid = threadIdx.x;
    for (int l = tid; l < 1024; l += 256) {
        int r = l >> 4, c4 = (l & 15) << 2;
        float4 ai = *(const float4*)&S[(size_t)(i0 + r) * d + k0 + c4];
        Ai[r][c4] = ai.x; Ai[r][c4 + 1] = ai.y; Ai[r][c4 + 2] = ai.z; Ai[r][c4 + 3] = ai.w;
        float4 aj = *(const float4*)&S[(size_t)(j0 + r) * d + k0 + c4];
        Aj[r][c4] = aj.x; Aj[r][c4 + 1] = aj.y; Aj[r][c4 + 2] = aj.z; Aj[r][c4 + 3] = aj.w;
    }
    __syncthreads();
    int tx = tid & 15, ty = tid >> 4;
    float acc[4][4] = {};
#pragma unroll 8
    for (int k = 0; k < 64; ++k) {
        float av[4], bv[4];
#pragma unroll
        for (int u = 0; u < 4; ++u) { av[u] = Ai[ty * 4 + u][k]; bv[u] = Aj[tx * 4 + u][k]; }
#pragma unroll
        for (int u = 0; u < 4; ++u)
#pragma unroll
            for (int v = 0; v < 4; ++v) acc[u][v] += av[u] * bv[v];
    }
#pragma unroll
    for (int u = 0; u < 4; ++u) {
        float4* p = (float4*)&S[(size_t)(i0 + ty * 4 + u) * d + j0 + tx * 4];
        float4 cv = *p;
        cv.x -= acc[u][0]; cv.y -= acc[u][1]; cv.z -= acc[u][2]; cv.w -= acc[u][3];
        *p = cv;
    }
}

// ---------------- res_av / res_va from means (attention collapsed) --------------
__global__ __launch_bounds__(256) void proj_mu_kernel(
    const float* __restrict__ mu_a, const float* __restrict__ mu_v,
    const void* __restrict__ Vvw, const void* __restrict__ Vvb,
    const void* __restrict__ Vaw, const void* __restrict__ Vab,
    float* __restrict__ res_av, float* __restrict__ res_va,
    const int* __restrict__ flag) {
    int bf = *flag;
    int b = blockIdx.x, tid = threadIdx.x;
    __shared__ float mv[DV_], ma[DA_];
    for (int i = tid; i < DV_; i += 256) mv[i] = mu_v[b * DV_ + i];
    for (int i = tid; i < DA_; i += 256) ma[i] = mu_a[b * DA_ + i];
    __syncthreads();
    for (int j = tid; j < DV_; j += 256) {
        size_t w = (size_t)j * DV_;
        float s = 0.f;
#pragma unroll 8
        for (int k = 0; k < DV_; ++k) s += mv[k] * ldx(Vvw, w + k, bf);
        res_av[b * DV_ + j] = s + ldx(Vvb, j, bf);
    }
    for (int j = tid; j < DA_; j += 256) {
        size_t w = (size_t)j * DA_;
        float s = 0.f;
#pragma unroll 8
        for (int k = 0; k < DA_; ++k) s += ma[k] * ldx(Vaw, w + k, bf);
        res_va[b * DA_ + j] = s + ldx(Vab, j, bf);
    }
}

// ---------------- lin_av / lin_va and gate constants ----------------------------
__global__ __launch_bounds__(256) void proj_res_kernel(
    const float* __restrict__ res_av, const float* __restrict__ res_va,
    const void* __restrict__ v2aw, const void* __restrict__ v2ab,
    const void* __restrict__ a2vw, const void* __restrict__ a2vb,
    const void* __restrict__ WAg, const void* __restrict__ bAg,
    const void* __restrict__ WVg, const void* __restrict__ bVg,
    float* __restrict__ lin_av, float* __restrict__ lin_va,
    float* __restrict__ gca, float* __restrict__ gcv,
    const int* __restrict__ flag) {
    int bf = *flag;
    int b = blockIdx.x, tid = threadIdx.x;
    __shared__ float rav[DV_], rva[DA_];
    __shared__ float red[256];
    for (int i = tid; i < DV_; i += 256) rav[i] = res_av[b * DV_ + i];
    for (int i = tid; i < DA_; i += 256) rva[i] = res_va[b * DA_ + i];
    __syncthreads();
    for (int dd = tid; dd < DA_; dd += 256) {
        size_t w = (size_t)dd * DV_;
        float s = 0.f;
#pragma unroll 8
        for (int k = 0; k < DV_; ++k) s += rav[k] * ldx(v2aw, w + k, bf);
        lin_av[b * DA_ + dd] = s + ldx(v2ab, dd, bf);
    }
    for (int dd = tid; dd < DV_; dd += 256) {
        size_t w = (size_t)dd * DA_;
        float s = 0.f;
#pragma unroll 8
        for (int k = 0; k < DA_; ++k) s += rva[k] * ldx(a2vw, w + k, bf);
        lin_va[b * DV_ + dd] = s + ldx(a2vb, dd, bf);
    }
    float pa = 0.f, pv = 0.f;
    for (int k = tid; k < DV_; k += 256) pa += rav[k] * ldx(WAg, DA_ + k, bf);
    for (int k = tid; k < DA_; k += 256) pv += rva[k] * ldx(WVg, DV_ + k, bf);
    red[tid] = pa; __syncthreads();
    for (int s = 128; s > 0; s >>= 1) { if (tid < s) red[tid] += red[tid + s]; __syncthreads(); }
    if (tid == 0) gca[b] = red[0] + ldx(bAg, 0, bf);
    __syncthreads();
    red[tid] = pv; __syncthreads();
    for (int s = 128; s > 0; s >>= 1) { if (tid < s) red[tid] += red[tid + s]; __syncthreads(); }
    if (tid == 0) gcv[b] = red[0] + ldx(bVg, 0, bf);
}

// ---------------- per-token gates -----------------------------------------------
__global__ __launch_bounds__(256) void gates_kernel(
    const void* __restrict__ A, const void* __restrict__ V,
    const void* __restrict__ WAg, const void* __restrict__ WVg,
    const float* __restrict__ gca, const float* __restrict__ gcv,
    float* __restrict__ g_a, float* __restrict__ g_v,
    const int* __restrict__ flag) {
    int bf = *flag;
    int bt = blockIdx.x;  // b*1024+t
    int b = bt >> 10;
    int tid = threadIdx.x;
    size_t Ar = (size_t)bt * DA_;
    size_t Vr = (size_t)bt * DV_;
    float sa = 0.f, sv = 0.f;
    for (int dd = tid; dd < DA_; dd += 256) sa += ldx(A, Ar + dd, bf) * ldx(WAg, dd, bf);
    for (int dd = tid; dd < DV_; dd += 256) sv += ldx(V, Vr + dd, bf) * ldx(WVg, dd, bf);
    __shared__ float ra[256], rv[256];
    ra[tid] = sa; rv[tid] = sv; __syncthreads();
    for (int s = 128; s > 0; s >>= 1) {
        if (tid < s) { ra[tid] += ra[tid + s]; rv[tid] += rv[tid + s]; }
        __syncthreads();
    }
    if (tid == 0) {
        g_a[bt] = 1.f / (1.f + expf(-(ra[0] + gca[b])));
        g_v[bt] = 1.f / (1.f + expf(-(rv[0] + gcv[b])));
    }
}

// ---- output: out = g*X + (1-g)*lin + eps @ L^T, eps generated inline -----------
__global__ __launch_bounds__(256) void out_kernel(
    const float* __restrict__ L, int D,
    const void* __restrict__ X, const float* __restrict__ g,
    const float* __restrict__ lin, void* __restrict__ out, int ocol0, int eoff,
    const int* __restrict__ flag) {
    int bf = *flag;
    int b = blockIdx.z;
    int t0 = blockIdx.x * 64, d0 = blockIdx.y * 64;
    int tid = threadIdx.x, tx = tid & 15, ty = tid >> 4;
    __shared__ float Et[16][65], Lt[16][65];
    const float* Lb = L + (size_t)b * D * D;
    float acc[4][4] = {};
    int emax = d0 + 64;  // L lower-triangular (upper zeroed) -> skip tiles above diag
    if (emax > D) emax = D;
    int row = tid >> 2, quad = tid & 3;
    for (int e0 = 0; e0 < emax; e0 += 16) {
        u32 ebase = ((u32)b * T_ + (u32)(t0 + row)) * (u32)DF_ + (u32)(eoff + e0 + quad * 4);
        const float* lp = Lb + (size_t)(d0 + row) * D + e0 + quad * 4;
#pragma unroll
        for (int u = 0; u < 4; ++u) {
            Et[quad * 4 + u][row] = gen_eps(ebase + u);
            Lt[quad * 4 + u][row] = lp[u];
        }
        __syncthreads();
#pragma unroll
        for (int kk = 0; kk < 16; ++kk) {
            float ev[4], lv[4];
#pragma unroll
            for (int u = 0; u < 4; ++u) { ev[u] = Et[kk][ty * 4 + u]; lv[u] = Lt[kk][tx * 4 + u]; }
#pragma unroll
            for (int u = 0; u < 4; ++u)
#pragma unroll
                for (int v = 0; v < 4; ++v) acc[u][v] += ev[u] * lv[v];
        }
        __syncthreads();
    }
#pragma unroll
    for (int u = 0; u < 4; ++u) {
        int t = t0 + ty * 4 + u;
        float gv = g[b * T_ + t];
        size_t Xrow = ((size_t)b * T_ + t) * D;
        size_t orow = ((size_t)b * T_ + t) * DF_ + ocol0;
#pragma unroll
        for (int v = 0; v < 4; ++v) {
            int dd = d0 + tx * 4 + v;
            float val = gv * ldx(X, Xrow + dd, bf) + (1.f - gv) * lin[b * D + dd] + acc[u][v];
            if (bf) ((u16*)out)[orow + dd] = f2b(val);
            else    ((float*)out)[orow + dd] = val;
        }
    }
}

extern "C" void kernel_launch(void* const* d_in, const int* in_sizes, int n_in,
                              void* d_out, int out_size, void* d_ws, size_t ws_size,
                              hipStream_t stream) {
    (void)in_sizes; (void)n_in; (void)out_size; (void)ws_size;
    const void* A    = d_in[0];
    const void* V    = d_in[1];
    const void* Vvw  = d_in[6];   // V_v_w
    const void* Vvb  = d_in[7];
    const void* Vaw  = d_in[12];  // V_a_w
    const void* Vab  = d_in[13];
    const void* WAg  = d_in[14];
    const void* bAg  = d_in[15];
    const void* WVg  = d_in[16];
    const void* bVg  = d_in[17];
    const void* v2aw = d_in[18];
    const void* v2ab = d_in[19];
    const void* a2vw = d_in[20];
    const void* a2vb = d_in[21];

    float* ws     = (float*)d_ws;
    float* LA     = ws;                    // 16*1024*1024
    float* LV     = LA + 16777216;         // 16*512*512
    float* mu_a   = LV + 4194304;          // 16*1024
    float* mu_v   = mu_a + 16384;          // 16*512
    float* res_av = mu_v + 8192;           // 16*512
    float* res_va = res_av + 8192;         // 16*1024
    float* lin_av = res_va + 16384;        // 16*1024
    float* lin_va = lin_av + 16384;        // 16*512
    float* gca    = lin_va + 8192;         // 16
    float* gcv    = gca + 16;              // 16
    float* g_a    = gcv + 16;              // 16*1024
    float* g_v    = g_a + 16384;           // 16*1024
    int*   dtf    = (int*)(g_v + 16384);
    // total ~84.3 MB of workspace

    detect_kernel<<<dim3(1), dim3(64), 0, stream>>>(A, dtf);
    means_kernel<<<dim3(96), dim3(256), 0, stream>>>(A, V, mu_a, mu_v, dtf);
    gram_kernel<<<dim3(16, 16, 16), dim3(256), 0, stream>>>(A, mu_a, LA, 1024, dtf);
    gram_kernel<<<dim3(8, 8, 16), dim3(256), 0, stream>>>(V, mu_v, LV, 512, dtf);
    // right-looking blocked Cholesky: 16 panel steps (V matrices finish at step 8)
    for (int s = 0; s < 16; ++s) {
        panel_kernel<<<dim3(32), dim3(256), 0, stream>>>(LA, LV, s);
        int mA = 15 - s;
        int tA = mA * (mA + 1) / 2;
        int mV = (s < 8) ? (7 - s) : 0;
        int tV = mV * (mV + 1) / 2;
        int tmax = tA > tV ? tA : tV;
        if (tmax > 0)
            trail_kernel<<<dim3(tmax, 1, 32), dim3(256), 0, stream>>>(LA, LV, s);
    }
    proj_mu_kernel<<<dim3(16), dim3(256), 0, stream>>>(mu_a, mu_v, Vvw, Vvb, Vaw, Vab,
                                                       res_av, res_va, dtf);
    proj_res_kernel<<<dim3(16), dim3(256), 0, stream>>>(res_av, res_va, v2aw, v2ab,
                                                        a2vw, a2vb, WAg, bAg, WVg, bVg,
                                                        lin_av, lin_va, gca, gcv, dtf);
    gates_kernel<<<dim3(16384), dim3(256), 0, stream>>>(A, V, WAg, WVg, gca, gcv,
                                                        g_a, g_v, dtf);
    out_kernel<<<dim3(16, 16, 16), dim3(256), 0, stream>>>(LA, 1024, A, g_a,
                                                           lin_av, d_out, 0, 0, dtf);
    out_kernel<<<dim3(16, 8, 16), dim3(256), 0, stream>>>(LV, 512, V, g_v,
                                                          lin_va, d_out, 1024, 1024, dtf);
}